// Round 7
// baseline (835.352 us; speedup 1.0000x reference)
//
#include <hip/hip_runtime.h>
#include <hip/hip_bf16.h>
#include <cstdint>
#include <cstddef>

#define N_NODES   100000
#define N_EDGES   3200000
#define IN_FEATS  256
#define N_HIDDEN  128
#define OUT_FEATS 40
#define H1_PITCH  64       // h1 row padded to 64 bf16 = 128 B (2 aligned lines)

// Bucket partition: bucket = dst >> 8 (256 nodes/bucket)
#define NB2       391      // ceil(100000/256); last bucket has 160 nodes
#define EPB       8192     // edges per partition block
#define NBLK      391      // ceil(3.2M/8192)
#define HIST_M    (NB2 * NBLK)   // 152,881

// gemm0 block-slice split across the 4 CSR-pipeline dispatches
#define GA 250
#define GB 50
#define GC 200
#define GD 125   // GA+GB+GC+GD = 625 = N_NODES/(32*5)

typedef __attribute__((ext_vector_type(8))) __bf16 bf16x8;
typedef __attribute__((ext_vector_type(4))) float f32x4;

// ---------------------------------------------------------------------------
// GEMM0 block body (MFMA): h0 = bf16(bf16(x) @ bf16(W0)), 32 rows x 128 cols
// per block-slot, 5 tiles/slot. bid in [0,625).
// ---------------------------------------------------------------------------
__device__ __forceinline__ void gemm0_block(
    int bid, const float* __restrict__ x, const float* __restrict__ W0,
    unsigned short* __restrict__ h0) {
  __shared__ __align__(16) unsigned short xb[32 * 264];
  const int tid  = threadIdx.x;
  const int lane = tid & 63;
  const int wave = tid >> 6;
  const int rb   = wave & 1;
  const int ch   = wave >> 1;
  const int l15  = lane & 15;
  const int g    = lane >> 4;

  bf16x8 Bf[4][8];
#pragma unroll
  for (int cb = 0; cb < 4; ++cb) {
    const int col = ch * 64 + cb * 16 + l15;
#pragma unroll
    for (int q = 0; q < 8; ++q) {
      const int k0 = q * 32 + g * 8;
      uint4 uw;
      {
        __hip_bfloat162 p;
        p.x = __float2bfloat16(W0[(size_t)(k0 + 0) * N_HIDDEN + col]);
        p.y = __float2bfloat16(W0[(size_t)(k0 + 1) * N_HIDDEN + col]);
        uw.x = *(unsigned int*)&p;
        p.x = __float2bfloat16(W0[(size_t)(k0 + 2) * N_HIDDEN + col]);
        p.y = __float2bfloat16(W0[(size_t)(k0 + 3) * N_HIDDEN + col]);
        uw.y = *(unsigned int*)&p;
        p.x = __float2bfloat16(W0[(size_t)(k0 + 4) * N_HIDDEN + col]);
        p.y = __float2bfloat16(W0[(size_t)(k0 + 5) * N_HIDDEN + col]);
        uw.z = *(unsigned int*)&p;
        p.x = __float2bfloat16(W0[(size_t)(k0 + 6) * N_HIDDEN + col]);
        p.y = __float2bfloat16(W0[(size_t)(k0 + 7) * N_HIDDEN + col]);
        uw.w = *(unsigned int*)&p;
      }
      Bf[cb][q] = __builtin_bit_cast(bf16x8, uw);
    }
  }

  for (int t = 0; t < 5; ++t) {
    const int row0 = (bid * 5 + t) * 32;
    __syncthreads();
    for (int i = tid; i < 32 * 128; i += 256) {
      const int row = i >> 7, kp = i & 127;
      const float2 v = *(const float2*)(x + (size_t)(row0 + row) * IN_FEATS + kp * 2);
      __hip_bfloat162 p;
      p.x = __float2bfloat16(v.x);
      p.y = __float2bfloat16(v.y);
      *(unsigned int*)&xb[row * 264 + kp * 2] = *(unsigned int*)&p;
    }
    __syncthreads();

    f32x4 acc[4];
#pragma unroll
    for (int cb = 0; cb < 4; ++cb) acc[cb] = (f32x4){0.f, 0.f, 0.f, 0.f};

#pragma unroll
    for (int q = 0; q < 8; ++q) {
      const bf16x8 a = *(const bf16x8*)&xb[(rb * 16 + l15) * 264 + q * 32 + g * 8];
      acc[0] = __builtin_amdgcn_mfma_f32_16x16x32_bf16(a, Bf[0][q], acc[0], 0, 0, 0);
      acc[1] = __builtin_amdgcn_mfma_f32_16x16x32_bf16(a, Bf[1][q], acc[1], 0, 0, 0);
      acc[2] = __builtin_amdgcn_mfma_f32_16x16x32_bf16(a, Bf[2][q], acc[2], 0, 0, 0);
      acc[3] = __builtin_amdgcn_mfma_f32_16x16x32_bf16(a, Bf[3][q], acc[3], 0, 0, 0);
    }

#pragma unroll
    for (int cb = 0; cb < 4; ++cb) {
      const int col = ch * 64 + cb * 16 + l15;
#pragma unroll
      for (int r = 0; r < 4; ++r) {
        const int row = row0 + rb * 16 + g * 4 + r;
        __hip_bfloat16 hb = __float2bfloat16(acc[cb][r]);
        h0[(size_t)row * N_HIDDEN + col] = *(unsigned short*)&hb;
      }
    }
  }
}

// ---------------------------------------------------------------------------
// CSR-build stage bodies (device functions, paired with gemm0 slices below).
// ---------------------------------------------------------------------------
__device__ __forceinline__ void p1hist_block(
    int blk, const int* __restrict__ dst, int* __restrict__ histG) {
  __shared__ int lh[NB2];
  const int tid = threadIdx.x;
  for (int i = tid; i < NB2; i += 256) lh[i] = 0;
  __syncthreads();

  const int e0 = blk * EPB;
  const int e1 = min(e0 + EPB, N_EDGES);
  for (int i = e0 + tid; i < e1; i += 256)
    atomicAdd(&lh[dst[i] >> 8], 1);
  __syncthreads();

  for (int i = tid; i < NB2; i += 256)
    histG[i * NBLK + blk] = lh[i];   // bucket-major for the scan
}

__device__ __forceinline__ void gscan256_block(int* __restrict__ histG) {
  __shared__ int partials[256];
  const int t = threadIdx.x;
  const int chunk = (HIST_M + 255) / 256;   // 598
  const int lo = t * chunk;
  const int hi = min(lo + chunk, HIST_M);

  int sum = 0;
  for (int i = lo; i < hi; ++i) sum += histG[i];
  partials[t] = sum;
  __syncthreads();

  for (int off = 1; off < 256; off <<= 1) {
    int v = (t >= off) ? partials[t - off] : 0;
    __syncthreads();
    partials[t] += v;
    __syncthreads();
  }

  int run = (t > 0) ? partials[t - 1] : 0;
  for (int i = lo; i < hi; ++i) {
    const int d = histG[i];
    histG[i] = run;
    run += d;
  }
}

__device__ __forceinline__ void p1scatter_block(
    int blk, const int* __restrict__ src, const int* __restrict__ dst,
    const float* __restrict__ ew, const int* __restrict__ histG,
    uint2* __restrict__ bucketed) {
  __shared__ int cur[NB2];
  const int tid = threadIdx.x;
  for (int i = tid; i < NB2; i += 256) cur[i] = histG[i * NBLK + blk];
  __syncthreads();

  const int e0 = blk * EPB;
  const int e1 = min(e0 + EPB, N_EDGES);
  for (int i = e0 + tid; i < e1; i += 256) {
    const int d = dst[i];
    const int b = d >> 8;
    const int pos = atomicAdd(&cur[b], 1);
    bucketed[pos] = make_uint2((unsigned)src[i] | ((unsigned)(d & 255) << 17),
                               __float_as_uint(ew[i]));
  }
}

__device__ __forceinline__ void p2place_block(
    int b, const uint2* __restrict__ bucketed, const int* __restrict__ histG,
    int* __restrict__ offsets, int2* __restrict__ srcw) {
  __shared__ int cnt[256];
  __shared__ int part[256];
  const int t = threadIdx.x;
  const int node0 = b << 8;
  const int beg = histG[b * NBLK];
  const int end = (b == NB2 - 1) ? N_EDGES : histG[(b + 1) * NBLK];

  cnt[t] = 0;
  __syncthreads();

  for (int j = beg + t; j < end; j += 256)
    atomicAdd(&cnt[bucketed[j].x >> 17], 1);
  __syncthreads();

  const int a = cnt[t];          // degree of node node0+t
  part[t] = a;
  __syncthreads();
  for (int off = 1; off < 256; off <<= 1) {
    int v = (t >= off) ? part[t - off] : 0;
    __syncthreads();
    part[t] += v;
    __syncthreads();
  }
  const int base = (t > 0) ? part[t - 1] : 0;

  const int o = beg + base;
  cnt[t] = o;                    // reuse as global cursor
  const int node = node0 + t;
  if (node < N_NODES) offsets[node] = o;
  if (b == NB2 - 1 && t == 0) offsets[N_NODES] = N_EDGES;
  __syncthreads();

  for (int j = beg + t; j < end; j += 256) {
    const uint2 en = bucketed[j];
    const int slot = atomicAdd(&cnt[en.x >> 17], 1);
    srcw[slot] = make_int2((int)(en.x & 0x1FFFFu), (int)en.y);
  }
}

// ---------------------------------------------------------------------------
// Pipeline dispatches: each CSR stage rides with a slice of gemm0.
// Chain: hist -> gscan -> scatter -> place -> gather0; gemm0 independent.
// ---------------------------------------------------------------------------
__global__ __launch_bounds__(256) void d1_hist_gemmA(
    const int* __restrict__ dst, int* __restrict__ histG,
    const float* __restrict__ x, const float* __restrict__ W0,
    unsigned short* __restrict__ h0) {
  if (blockIdx.x < NBLK) p1hist_block(blockIdx.x, dst, histG);
  else                   gemm0_block(blockIdx.x - NBLK, x, W0, h0);           // 0..249
}

__global__ __launch_bounds__(256) void d2_gscan_gemmB(
    int* __restrict__ histG,
    const float* __restrict__ x, const float* __restrict__ W0,
    unsigned short* __restrict__ h0) {
  if (blockIdx.x == 0) gscan256_block(histG);
  else                 gemm0_block(GA + blockIdx.x - 1, x, W0, h0);           // 250..299
}

__global__ __launch_bounds__(256) void d3_scatter_gemmC(
    const int* __restrict__ src, const int* __restrict__ dst,
    const float* __restrict__ ew, const int* __restrict__ histG,
    uint2* __restrict__ bucketed,
    const float* __restrict__ x, const float* __restrict__ W0,
    unsigned short* __restrict__ h0) {
  if (blockIdx.x < NBLK) p1scatter_block(blockIdx.x, src, dst, ew, histG, bucketed);
  else                   gemm0_block(GA + GB + blockIdx.x - NBLK, x, W0, h0); // 300..499
}

__global__ __launch_bounds__(256) void d4_place_gemmD(
    const uint2* __restrict__ bucketed, const int* __restrict__ histG,
    int* __restrict__ offsets, int2* __restrict__ srcw,
    const float* __restrict__ x, const float* __restrict__ W0,
    unsigned short* __restrict__ h0) {
  if (blockIdx.x < NB2) p2place_block(blockIdx.x, bucketed, histG, offsets, srcw);
  else                  gemm0_block(GA + GB + GC + blockIdx.x - NB2, x, W0, h0); // 500..624
}

// ---------------------------------------------------------------------------
// Fused gather0 + bias + ReLU + GEMM1 (8-edge MLP batches) — unchanged (control).
// ---------------------------------------------------------------------------
__global__ __launch_bounds__(256) void gather0_gemm1_kernel(
    const unsigned int* __restrict__ h0b2, const int2* __restrict__ srcw,
    const int* __restrict__ offsets, const float* __restrict__ b0,
    const float* __restrict__ W1, unsigned short* __restrict__ h1b) {
  __shared__ float hs[4][N_HIDDEN];
  const int wave = threadIdx.x >> 6;
  const int lane = threadIdx.x & 63;
  const int node = blockIdx.x * 4 + wave;

  const int beg = __builtin_amdgcn_readfirstlane(offsets[node]);
  const int end = __builtin_amdgcn_readfirstlane(offsets[node + 1]);
  const int f   = lane * 2;

  float ax = 0.f, ay = 0.f;
  int j = beg;
  for (; j + 8 <= end; j += 8) {
    const int2 s0 = srcw[j];
    const int2 s1 = srcw[j + 1];
    const int2 s2 = srcw[j + 2];
    const int2 s3 = srcw[j + 3];
    const int2 s4 = srcw[j + 4];
    const int2 s5 = srcw[j + 5];
    const int2 s6 = srcw[j + 6];
    const int2 s7 = srcw[j + 7];
    const unsigned int u0 = h0b2[(size_t)s0.x * 64 + lane];
    const unsigned int u1 = h0b2[(size_t)s1.x * 64 + lane];
    const unsigned int u2 = h0b2[(size_t)s2.x * 64 + lane];
    const unsigned int u3 = h0b2[(size_t)s3.x * 64 + lane];
    const unsigned int u4 = h0b2[(size_t)s4.x * 64 + lane];
    const unsigned int u5 = h0b2[(size_t)s5.x * 64 + lane];
    const unsigned int u6 = h0b2[(size_t)s6.x * 64 + lane];
    const unsigned int u7 = h0b2[(size_t)s7.x * 64 + lane];
    ax = fmaf(__uint_as_float(u0 << 16),          __int_as_float(s0.y), ax);
    ay = fmaf(__uint_as_float(u0 & 0xFFFF0000u),  __int_as_float(s0.y), ay);
    ax = fmaf(__uint_as_float(u1 << 16),          __int_as_float(s1.y), ax);
    ay = fmaf(__uint_as_float(u1 & 0xFFFF0000u),  __int_as_float(s1.y), ay);
    ax = fmaf(__uint_as_float(u2 << 16),          __int_as_float(s2.y), ax);
    ay = fmaf(__uint_as_float(u2 & 0xFFFF0000u),  __int_as_float(s2.y), ay);
    ax = fmaf(__uint_as_float(u3 << 16),          __int_as_float(s3.y), ax);
    ay = fmaf(__uint_as_float(u3 & 0xFFFF0000u),  __int_as_float(s3.y), ay);
    ax = fmaf(__uint_as_float(u4 << 16),          __int_as_float(s4.y), ax);
    ay = fmaf(__uint_as_float(u4 & 0xFFFF0000u),  __int_as_float(s4.y), ay);
    ax = fmaf(__uint_as_float(u5 << 16),          __int_as_float(s5.y), ax);
    ay = fmaf(__uint_as_float(u5 & 0xFFFF0000u),  __int_as_float(s5.y), ay);
    ax = fmaf(__uint_as_float(u6 << 16),          __int_as_float(s6.y), ax);
    ay = fmaf(__uint_as_float(u6 & 0xFFFF0000u),  __int_as_float(s6.y), ay);
    ax = fmaf(__uint_as_float(u7 << 16),          __int_as_float(s7.y), ax);
    ay = fmaf(__uint_as_float(u7 & 0xFFFF0000u),  __int_as_float(s7.y), ay);
  }
  for (; j < end; ++j) {
    const int2 s0 = srcw[j];
    const unsigned int u0 = h0b2[(size_t)s0.x * 64 + lane];
    ax = fmaf(__uint_as_float(u0 << 16),         __int_as_float(s0.y), ax);
    ay = fmaf(__uint_as_float(u0 & 0xFFFF0000u), __int_as_float(s0.y), ay);
  }

  const float v0 = ax + b0[f];
  const float v1 = ay + b0[f + 1];
  hs[wave][f]     = v0 > 0.f ? v0 : 0.f;
  hs[wave][f + 1] = v1 > 0.f ? v1 : 0.f;
  __syncthreads();

  unsigned short w16 = 0;
  if (lane < OUT_FEATS) {
    float o = 0.f;
#pragma unroll 8
    for (int k = 0; k < N_HIDDEN; ++k)
      o = fmaf(hs[wave][k], W1[k * OUT_FEATS + lane], o);
    __hip_bfloat16 hb = __float2bfloat16(o);
    w16 = *(unsigned short*)&hb;
  }
  h1b[(size_t)node * H1_PITCH + lane] = w16;   // pad lanes write 0: full lines
}

// ---------------------------------------------------------------------------
// Fused gather1 + bias + log_softmax — unchanged (control).
// ---------------------------------------------------------------------------
__global__ __launch_bounds__(256) void gather1_lsm_kernel(
    const unsigned short* __restrict__ h1b, const int2* __restrict__ srcw,
    const int* __restrict__ offsets, const float* __restrict__ b1,
    float* __restrict__ out) {
  const int wave = threadIdx.x >> 6;
  const int lane = threadIdx.x & 63;
  const int node = blockIdx.x * 4 + wave;

  const int beg = __builtin_amdgcn_readfirstlane(offsets[node]);
  const int end = __builtin_amdgcn_readfirstlane(offsets[node + 1]);

  float acc = 0.f;
  if (lane < OUT_FEATS) {
    int j = beg;
    for (; j + 8 <= end; j += 8) {
      const int2 s0 = srcw[j];
      const int2 s1 = srcw[j + 1];
      const int2 s2 = srcw[j + 2];
      const int2 s3 = srcw[j + 3];
      const int2 s4 = srcw[j + 4];
      const int2 s5 = srcw[j + 5];
      const int2 s6 = srcw[j + 6];
      const int2 s7 = srcw[j + 7];
      const unsigned int u0 = h1b[(size_t)s0.x * H1_PITCH + lane];
      const unsigned int u1 = h1b[(size_t)s1.x * H1_PITCH + lane];
      const unsigned int u2 = h1b[(size_t)s2.x * H1_PITCH + lane];
      const unsigned int u3 = h1b[(size_t)s3.x * H1_PITCH + lane];
      const unsigned int u4 = h1b[(size_t)s4.x * H1_PITCH + lane];
      const unsigned int u5 = h1b[(size_t)s5.x * H1_PITCH + lane];
      const unsigned int u6 = h1b[(size_t)s6.x * H1_PITCH + lane];
      const unsigned int u7 = h1b[(size_t)s7.x * H1_PITCH + lane];
      acc = fmaf(__uint_as_float(u0 << 16), __int_as_float(s0.y), acc);
      acc = fmaf(__uint_as_float(u1 << 16), __int_as_float(s1.y), acc);
      acc = fmaf(__uint_as_float(u2 << 16), __int_as_float(s2.y), acc);
      acc = fmaf(__uint_as_float(u3 << 16), __int_as_float(s3.y), acc);
      acc = fmaf(__uint_as_float(u4 << 16), __int_as_float(s4.y), acc);
      acc = fmaf(__uint_as_float(u5 << 16), __int_as_float(s5.y), acc);
      acc = fmaf(__uint_as_float(u6 << 16), __int_as_float(s6.y), acc);
      acc = fmaf(__uint_as_float(u7 << 16), __int_as_float(s7.y), acc);
    }
    for (; j < end; ++j) {
      const int2 s0 = srcw[j];
      const unsigned int u0 = h1b[(size_t)s0.x * H1_PITCH + lane];
      acc = fmaf(__uint_as_float(u0 << 16), __int_as_float(s0.y), acc);
    }
    acc += b1[lane];
  } else {
    acc = -INFINITY;
  }

  float m = acc;
#pragma unroll
  for (int off = 32; off > 0; off >>= 1) m = fmaxf(m, __shfl_xor(m, off));

  float s = (lane < OUT_FEATS) ? expf(acc - m) : 0.f;
#pragma unroll
  for (int off = 32; off > 0; off >>= 1) s += __shfl_xor(s, off);

  if (lane < OUT_FEATS)
    out[(size_t)node * OUT_FEATS + lane] = acc - m - logf(s);
}

// ---------------------------------------------------------------------------
extern "C" void kernel_launch(void* const* d_in, const int* in_sizes, int n_in,
                              void* d_out, int out_size, void* d_ws, size_t ws_size,
                              hipStream_t stream) {
  const float* x   = (const float*)d_in[0];
  const float* W0  = (const float*)d_in[1];
  const float* b0  = (const float*)d_in[2];
  const float* W1  = (const float*)d_in[3];
  const float* b1  = (const float*)d_in[4];
  const float* ew  = (const float*)d_in[5];
  const int*   src = (const int*)d_in[6];
  const int*   dst = (const int*)d_in[7];
  float* out = (float*)d_out;

  // Workspace layout, peak ~90.6 MB (ws >= 102.4 MB proven in R1):
  //   h0b2     [0,          25,600,000)   N*128 bf16
  //   srcw     [25,600,000, 51,200,000)   E int2, dst-sorted
  //   bucketed [51,200,000, 76,800,000)   E uint2, bucket-partitioned
  //   offsets  [76,800,000, 77,200,064)   N+1 int
  //   histG    [77,200,064, 77,811,648)   NB2*NBLK int (611,524 B used)
  //   h1b      [77,811,648, 90,611,648)   N*64 bf16 (pitch-64, 128B rows)
  char* ws = (char*)d_ws;
  unsigned int* h0b2 = (unsigned int*)(ws);
  int2*  srcw     = (int2*)(ws + 25600000);
  uint2* bucketed = (uint2*)(ws + 51200000);
  int*   offsets  = (int*)(ws + 76800000);
  int*   histG    = (int*)(ws + 77200064);
  unsigned short* h1b = (unsigned short*)(ws + 77811648);
  unsigned short* h0s = (unsigned short*)h0b2;

  // CSR build pipelined under gemm0 (slices GA/GB/GC/GD of 625 blocks).
  d1_hist_gemmA<<<NBLK + GA, 256, 0, stream>>>(dst, histG, x, W0, h0s);
  d2_gscan_gemmB<<<1 + GB, 256, 0, stream>>>(histG, x, W0, h0s);
  d3_scatter_gemmC<<<NBLK + GC, 256, 0, stream>>>(src, dst, ew, histG, bucketed, x, W0, h0s);
  d4_place_gemmD<<<NB2 + GD, 256, 0, stream>>>(bucketed, histG, offsets, srcw, x, W0, h0s);

  gather0_gemm1_kernel<<<N_NODES / 4, 256, 0, stream>>>(h0b2, srcw, offsets, b0, W1, h1b);
  gather1_lsm_kernel<<<N_NODES / 4, 256, 0, stream>>>(h1b, srcw, offsets, b1, out);
}